// Round 1
// 762.569 us; speedup vs baseline: 1.0973x; 1.0973x over previous
//
#include <hip/hip_runtime.h>
#include <math.h>

#define N_TOK   262144
#define DIMV    128
#define KCODE   1024
#define LEV     3
#define BLOCK   256
#define NTILES  64          // 16-code tiles per level
#define EPS     0.08f       // fp16 2-product distance error band (~40 sigma)

typedef _Float16 f16x8 __attribute__((ext_vector_type(8)));
typedef float f32x4 __attribute__((ext_vector_type(4)));

// ws layout: double ws[0] = loss accum; double ee64[3072] @ ws+8;
//            float ee32b[3072] (= float(ee64 + 8192)) @ (float*)(ws + 8 + 3072)

__global__ void rvq_prep(const float* __restrict__ cb, double* __restrict__ ws) {
    int c = blockIdx.x * blockDim.x + threadIdx.x;
    if (c == 0) ws[0] = 0.0;
    if (c < LEV * KCODE) {
        const float* e = cb + (size_t)c * DIMV;
        double s = 0.0;
        #pragma unroll 8
        for (int j = 0; j < DIMV; ++j) { double v = (double)e[j]; s = fma(v, v, s); }
        ws[8 + c] = s;
        ((float*)(ws + 8 + LEV * KCODE))[c] = (float)(s + 8192.0);
    }
}

// woff precomputed: chunk c = (ks<<6)|(lidx), swizzled c' = c ^ ((c>>4)&7) to spread
// each 8-lane LDS write phase across all 8 bank-groups (was: 8-way conflict, 56 extra cy).
__device__ inline void stage_write(unsigned char* dst, int woff, float4 g0, float4 g1) {
    f16x8 v;
    v[0]=(_Float16)g0.x; v[1]=(_Float16)g0.y; v[2]=(_Float16)g0.z; v[3]=(_Float16)g0.w;
    v[4]=(_Float16)g1.x; v[5]=(_Float16)g1.y; v[6]=(_Float16)g1.z; v[7]=(_Float16)g1.w;
    *(f16x8*)(dst + woff) = v;
}

__device__ inline unsigned sel4(const unsigned v[4], int j) {
    unsigned a = (j & 1) ? v[1] : v[0];
    unsigned b = (j & 1) ? v[3] : v[2];
    return (j & 2) ? b : a;
}

__global__ __launch_bounds__(BLOCK, 2) void rvq_main(const float* __restrict__ ze,
                                                     const float* __restrict__ cb,
                                                     float* __restrict__ out,
                                                     double* __restrict__ ws) {
    __shared__ __align__(16) unsigned char Bbuf[2][4096];
    __shared__ __align__(16) float eeS[KCODE];
    __shared__ double ssum[4];

    const double* __restrict__ ee64g = ws + 8;
    const float*  __restrict__ eebg  = (const float*)(ws + 8 + LEV * KCODE);

    const int tid  = threadIdx.x;
    const int lane = tid & 63;
    const int wid  = tid >> 6;
    const int q    = lane >> 4;   // quad: owns dims st*32 + q*8 + j
    const int col  = lane & 15;   // A-operand row (token), B-operand col (code)
    const long tokbase = (long)blockIdx.x * 128 + wid * 32;

    // --- swizzled LDS offsets (bank-conflict-free staging, see stage_write) ---
    const int wc   = (((tid >> 2) & 3) << 6) | ((tid & 3) << 4) | (tid >> 4);
    const int woff = (wc ^ ((wc >> 4) & 7)) << 4;
    const int ro_e = (lane ^ (lane >> 4)) << 4;        // read offset, even ksteps (0,2)
    const int ro_o = (lane ^ 4 ^ (lane >> 4)) << 4;    // read offset, odd ksteps (1,3)

    float r[2][4][8];             // residual, fp32, reference-exact op chain
    f16x8 Ah[2][4], Al[2][4];     // A-frags: hi/lo fp16 split, per Mtile per kstep

    #pragma unroll
    for (int mt = 0; mt < 2; ++mt) {
        const float4* zp = (const float4*)(ze + (size_t)(tokbase + mt*16 + col) * DIMV);
        #pragma unroll
        for (int st = 0; st < 4; ++st) {
            float4 a = zp[st*8 + q*2], b = zp[st*8 + q*2 + 1];
            r[mt][st][0]=a.x; r[mt][st][1]=a.y; r[mt][st][2]=a.z; r[mt][st][3]=a.w;
            r[mt][st][4]=b.x; r[mt][st][5]=b.y; r[mt][st][6]=b.z; r[mt][st][7]=b.w;
        }
    }
    #pragma unroll
    for (int mt = 0; mt < 2; ++mt)
        #pragma unroll
        for (int st = 0; st < 4; ++st) {
            f16x8 h, lo;
            #pragma unroll
            for (int j = 0; j < 8; ++j) {
                float x = r[mt][st][j];
                _Float16 hh = (_Float16)x;
                h[j] = hh;
                lo[j] = (_Float16)(x - (float)hh);
            }
            Ah[mt][st] = h; Al[mt][st] = lo;
        }

    double loss = 0.0;
    float* out_idx = out + (size_t)N_TOK * DIMV + 2;

    for (int l = 0; l < LEV; ++l) {
        __syncthreads();   // prior level's LDS users done
        ((float4*)eeS)[tid] = ((const float4*)(eebg + (size_t)l * KCODE))[tid];
        float4 g0, g1;
        {   // stage tile 0
            const float4* p = (const float4*)(cb + ((size_t)l*KCODE + (tid>>4)) * DIMV + (tid&15)*8);
            g0 = p[0]; g1 = p[1];
            stage_write(Bbuf[0], woff, g0, g1);
        }
        __syncthreads();

        unsigned m1[2][4], m2[2][4];
        #pragma unroll
        for (int mt = 0; mt < 2; ++mt)
            #pragma unroll
            for (int i = 0; i < 4; ++i) { m1[mt][i] = 0xFFFFFFFFu; m2[mt][i] = 0xFFFFFFFFu; }

        for (int t = 0; t < NTILES; ++t) {
            if (t < NTILES - 1) {
                const float4* p = (const float4*)(cb + ((size_t)l*KCODE + (t+1)*16 + (tid>>4)) * DIMV + (tid&15)*8);
                g0 = p[0]; g1 = p[1];
            }
            {
                const unsigned char* bb = Bbuf[t & 1];
                f16x8 B0 = *(const f16x8*)(bb + ro_e);
                f16x8 B1 = *(const f16x8*)(bb + 1024 + ro_o);
                f16x8 B2 = *(const f16x8*)(bb + 2048 + ro_e);
                f16x8 B3 = *(const f16x8*)(bb + 3072 + ro_o);
                float eeq = eeS[t*16 + col];
                f32x4 c0 = {0.f,0.f,0.f,0.f}, c1v = {0.f,0.f,0.f,0.f};
                c0  = __builtin_amdgcn_mfma_f32_16x16x32_f16(Ah[0][0], B0, c0, 0,0,0);
                c0  = __builtin_amdgcn_mfma_f32_16x16x32_f16(Al[0][0], B0, c0, 0,0,0);
                c1v = __builtin_amdgcn_mfma_f32_16x16x32_f16(Ah[1][0], B0, c1v, 0,0,0);
                c1v = __builtin_amdgcn_mfma_f32_16x16x32_f16(Al[1][0], B0, c1v, 0,0,0);
                c0  = __builtin_amdgcn_mfma_f32_16x16x32_f16(Ah[0][1], B1, c0, 0,0,0);
                c0  = __builtin_amdgcn_mfma_f32_16x16x32_f16(Al[0][1], B1, c0, 0,0,0);
                c1v = __builtin_amdgcn_mfma_f32_16x16x32_f16(Ah[1][1], B1, c1v, 0,0,0);
                c1v = __builtin_amdgcn_mfma_f32_16x16x32_f16(Al[1][1], B1, c1v, 0,0,0);
                c0  = __builtin_amdgcn_mfma_f32_16x16x32_f16(Ah[0][2], B2, c0, 0,0,0);
                c0  = __builtin_amdgcn_mfma_f32_16x16x32_f16(Al[0][2], B2, c0, 0,0,0);
                c1v = __builtin_amdgcn_mfma_f32_16x16x32_f16(Ah[1][2], B2, c1v, 0,0,0);
                c1v = __builtin_amdgcn_mfma_f32_16x16x32_f16(Al[1][2], B2, c1v, 0,0,0);
                c0  = __builtin_amdgcn_mfma_f32_16x16x32_f16(Ah[0][3], B3, c0, 0,0,0);
                c0  = __builtin_amdgcn_mfma_f32_16x16x32_f16(Al[0][3], B3, c0, 0,0,0);
                c1v = __builtin_amdgcn_mfma_f32_16x16x32_f16(Ah[1][3], B3, c1v, 0,0,0);
                c1v = __builtin_amdgcn_mfma_f32_16x16x32_f16(Al[1][3], B3, c1v, 0,0,0);
                #pragma unroll
                for (int i = 0; i < 4; ++i) {
                    unsigned k0 = (__float_as_uint(fmaf(-2.0f, c0[i],  eeq)) << 6) | (unsigned)t;
                    m2[0][i] = min(m2[0][i], max(m1[0][i], k0));
                    m1[0][i] = min(m1[0][i], k0);
                    unsigned k1_ = (__float_as_uint(fmaf(-2.0f, c1v[i], eeq)) << 6) | (unsigned)t;
                    m2[1][i] = min(m2[1][i], max(m1[1][i], k1_));
                    m1[1][i] = min(m1[1][i], k1_);
                }
            }
            if (t < NTILES - 1) stage_write(Bbuf[(t+1)&1], woff, g0, g1);
            __syncthreads();
        }

        // ---- phase 2: cross-lane top-2 reduce (with lane-col meta), select, rescore, update ----
        unsigned k1[2][4], k2[2][4], q1[2][4], q2[2][4];
        #pragma unroll
        for (int mt = 0; mt < 2; ++mt)
            #pragma unroll
            for (int i = 0; i < 4; ++i) {
                k1[mt][i] = m1[mt][i]; k2[mt][i] = m2[mt][i];
                q1[mt][i] = (unsigned)col; q2[mt][i] = (unsigned)col;
            }
        #pragma unroll
        for (int d = 1; d <= 8; d <<= 1) {
            #pragma unroll
            for (int mt = 0; mt < 2; ++mt)
                #pragma unroll
                for (int i = 0; i < 4; ++i) {
                    unsigned ok1 = __shfl_xor(k1[mt][i], d), oq1 = __shfl_xor(q1[mt][i], d);
                    unsigned ok2 = __shfl_xor(k2[mt][i], d), oq2 = __shfl_xor(q2[mt][i], d);
                    bool sw = (ok1 < k1[mt][i]) || (ok1 == k1[mt][i] && oq1 < q1[mt][i]);
                    unsigned n1 = sw ? ok1 : k1[mt][i], nq1 = sw ? oq1 : q1[mt][i];
                    unsigned hk = sw ? k1[mt][i] : ok1, hq = sw ? q1[mt][i] : oq1;
                    bool s2 = (ok2 < k2[mt][i]) || (ok2 == k2[mt][i] && oq2 < q2[mt][i]);
                    unsigned p2 = s2 ? ok2 : k2[mt][i], pq = s2 ? oq2 : q2[mt][i];
                    bool s3 = (p2 < hk) || (p2 == hk && pq < hq);
                    k1[mt][i] = n1;              q1[mt][i] = nq1;
                    k2[mt][i] = s3 ? p2 : hk;    q2[mt][i] = s3 ? pq : hq;
                }
        }

        int jsel = (lane >> 2) & 3;
        int S = ((col >> 2) << 4) | ((col & 3) << 2);   // source lane holding token col's keys

        #pragma unroll
        for (int mt = 0; mt < 2; ++mt) {
            unsigned sk1 = sel4(k1[mt], jsel), sq1 = sel4(q1[mt], jsel);
            unsigned sk2 = sel4(k2[mt], jsel), sq2 = sel4(q2[mt], jsel);
            unsigned bk1 = (unsigned)__shfl((int)sk1, S);
            unsigned bq1 = (unsigned)__shfl((int)sq1, S);
            unsigned bk2 = (unsigned)__shfl((int)sk2, S);
            unsigned bq2 = (unsigned)__shfl((int)sq2, S);
            int c1c = (int)(((bk1 & 63u) << 4) | bq1);
            int c2c = (int)(((bk2 & 63u) << 4) | bq2);
            float d1 = __uint_as_float((bk1 >> 6) | 0x44000000u) - 8192.0f;
            float d2 = __uint_as_float((bk2 >> 6) | 0x44000000u) - 8192.0f;
            int bc = c1c;
            if (d2 - d1 < EPS) {   // ambiguous: exact fp64 rescore of both (uniform per token group)
                double s1 = 0.0, s2d = 0.0;
                const float4* e1 = (const float4*)(cb + ((size_t)l*KCODE + c1c)*DIMV);
                const float4* e2 = (const float4*)(cb + ((size_t)l*KCODE + c2c)*DIMV);
                #pragma unroll
                for (int st = 0; st < 4; ++st) {
                    float4 a = e1[st*8 + q*2], b = e1[st*8 + q*2 + 1];
                    s1 = fma((double)a.x,(double)r[mt][st][0],s1); s1 = fma((double)a.y,(double)r[mt][st][1],s1);
                    s1 = fma((double)a.z,(double)r[mt][st][2],s1); s1 = fma((double)a.w,(double)r[mt][st][3],s1);
                    s1 = fma((double)b.x,(double)r[mt][st][4],s1); s1 = fma((double)b.y,(double)r[mt][st][5],s1);
                    s1 = fma((double)b.z,(double)r[mt][st][6],s1); s1 = fma((double)b.w,(double)r[mt][st][7],s1);
                    float4 a2 = e2[st*8 + q*2], b2 = e2[st*8 + q*2 + 1];
                    s2d = fma((double)a2.x,(double)r[mt][st][0],s2d); s2d = fma((double)a2.y,(double)r[mt][st][1],s2d);
                    s2d = fma((double)a2.z,(double)r[mt][st][2],s2d); s2d = fma((double)a2.w,(double)r[mt][st][3],s2d);
                    s2d = fma((double)b2.x,(double)r[mt][st][4],s2d); s2d = fma((double)b2.y,(double)r[mt][st][5],s2d);
                    s2d = fma((double)b2.z,(double)r[mt][st][6],s2d); s2d = fma((double)b2.w,(double)r[mt][st][7],s2d);
                }
                s1  += __shfl_xor(s1, 16);  s1  += __shfl_xor(s1, 32);
                s2d += __shfl_xor(s2d, 16); s2d += __shfl_xor(s2d, 32);
                double dd1 = ee64g[l*KCODE + c1c] - 2.0*s1;
                double dd2 = ee64g[l*KCODE + c2c] - 2.0*s2d;
                if (dd2 < dd1 || (dd2 == dd1 && c2c < c1c)) bc = c2c;
            }
            // residual update: reference-exact fp32 op chain
            const float4* eb = (const float4*)(cb + ((size_t)l*KCODE + bc)*DIMV);
            #pragma unroll
            for (int st = 0; st < 4; ++st) {
                float4 a = eb[st*8 + q*2], b = eb[st*8 + q*2 + 1];
                float qv[8] = {a.x,a.y,a.z,a.w,b.x,b.y,b.z,b.w};
                #pragma unroll
                for (int j = 0; j < 8; ++j) {
                    float rv = r[mt][st][j];
                    float t1 = qv[j] - rv;              // z_q - residual
                    loss += (double)t1 * (double)t1;
                    float zqst = rv + t1;               // straight-through
                    r[mt][st][j] = rv - zqst;
                }
            }
            if (l < LEV - 1) {   // rebuild A-frags for next level
                #pragma unroll
                for (int st = 0; st < 4; ++st) {
                    f16x8 h, lo;
                    #pragma unroll
                    for (int j = 0; j < 8; ++j) {
                        float x = r[mt][st][j];
                        _Float16 hh = (_Float16)x;
                        h[j] = hh;
                        lo[j] = (_Float16)(x - (float)hh);
                    }
                    Ah[mt][st] = h; Al[mt][st] = lo;
                }
            } else {             // final output: z_q_total = z_e - residual_final
                const float4* zp = (const float4*)(ze + (size_t)(tokbase + mt*16 + col)*DIMV);
                float4* op = (float4*)(out + (size_t)(tokbase + mt*16 + col)*DIMV);
                #pragma unroll
                for (int st = 0; st < 4; ++st) {
                    float4 za = zp[st*8 + q*2], zb = zp[st*8 + q*2 + 1];
                    float4 oa, ob;
                    oa.x = za.x - r[mt][st][0]; oa.y = za.y - r[mt][st][1];
                    oa.z = za.z - r[mt][st][2]; oa.w = za.w - r[mt][st][3];
                    ob.x = zb.x - r[mt][st][4]; ob.y = zb.y - r[mt][st][5];
                    ob.z = zb.z - r[mt][st][6]; ob.w = zb.w - r[mt][st][7];
                    op[st*8 + q*2] = oa; op[st*8 + q*2 + 1] = ob;
                }
            }
            if (q == 0) out_idx[(size_t)(tokbase + mt*16 + col)*3 + l] = (float)bc;
        }
    }

    #pragma unroll
    for (int d = 1; d <= 32; d <<= 1) loss += __shfl_xor(loss, d);
    if ((tid & 63) == 0) ssum[wid] = loss;
    __syncthreads();
    if (tid == 0) atomicAdd(ws, ssum[0] + ssum[1] + ssum[2] + ssum[3]);
}

__global__ void rvq_fin(const double* __restrict__ ws, float* __restrict__ out) {
    double vq = ws[0] / ((double)N_TOK * (double)DIMV * (double)LEV);
    out[(size_t)N_TOK * DIMV + 0] = (float)vq;
    out[(size_t)N_TOK * DIMV + 1] = (float)(0.25 * vq);
}

extern "C" void kernel_launch(void* const* d_in, const int* in_sizes, int n_in,
                              void* d_out, int out_size, void* d_ws, size_t ws_size,
                              hipStream_t stream) {
    const float* ze = (const float*)d_in[0];
    const float* cb = (const float*)d_in[1];
    float* out = (float*)d_out;
    double* ws = (double*)d_ws;

    rvq_prep<<<(LEV * KCODE + 255) / 256, 256, 0, stream>>>(cb, ws);
    rvq_main<<<N_TOK / 128, BLOCK, 0, stream>>>(ze, cb, out, ws);
    rvq_fin<<<1, 1, 0, stream>>>(ws, out);
}

// Round 2
// 708.407 us; speedup vs baseline: 1.1812x; 1.0765x over previous
//
#include <hip/hip_runtime.h>
#include <math.h>

#define N_TOK   262144
#define DIMV    128
#define KCODE   1024
#define LEV     3
#define BLOCK   256
#define NTILES  64          // 16-code tiles per level
#define EPS     0.08f       // fp16 2-product distance error band (~40 sigma)

typedef _Float16 f16x8 __attribute__((ext_vector_type(8)));
typedef float f32x4 __attribute__((ext_vector_type(4)));

// ws layout: double ws[0] = loss accum; double ee64[3072] @ ws+8;
//            float ee32b[3072] (= float(ee64 + 8192)) @ (float*)(ws + 8 + 3072)

__global__ void rvq_prep(const float* __restrict__ cb, double* __restrict__ ws) {
    int c = blockIdx.x * blockDim.x + threadIdx.x;
    if (c == 0) ws[0] = 0.0;
    if (c < LEV * KCODE) {
        const float* e = cb + (size_t)c * DIMV;
        double s = 0.0;
        #pragma unroll 8
        for (int j = 0; j < DIMV; ++j) { double v = (double)e[j]; s = fma(v, v, s); }
        ws[8 + c] = s;
        ((float*)(ws + 8 + LEV * KCODE))[c] = (float)(s + 8192.0);
    }
}

// woff precomputed: chunk c = (ks<<6)|(lidx), swizzled c' = c ^ ((c>>4)&7) to spread
// each 8-lane LDS write phase across all 8 bank-groups (bank-conflict-free, verified R1).
__device__ inline void stage_write(unsigned char* dst, int woff, float4 g0, float4 g1) {
    f16x8 v;
    v[0]=(_Float16)g0.x; v[1]=(_Float16)g0.y; v[2]=(_Float16)g0.z; v[3]=(_Float16)g0.w;
    v[4]=(_Float16)g1.x; v[5]=(_Float16)g1.y; v[6]=(_Float16)g1.z; v[7]=(_Float16)g1.w;
    *(f16x8*)(dst + woff) = v;
}

__device__ inline unsigned sel4(const unsigned v[4], int j) {
    unsigned a = (j & 1) ? v[1] : v[0];
    unsigned b = (j & 1) ? v[3] : v[2];
    return (j & 2) ? b : a;
}

__global__ __launch_bounds__(BLOCK, 2) void rvq_main(const float* __restrict__ ze,
                                                     const float* __restrict__ cb,
                                                     float* __restrict__ out,
                                                     double* __restrict__ ws) {
    __shared__ __align__(16) unsigned char Bbuf[8][4096];   // 8-deep ring: barrier per 4 tiles
    __shared__ __align__(16) float eeS[KCODE];
    __shared__ double ssum[4];

    const double* __restrict__ ee64g = ws + 8;
    const float*  __restrict__ eebg  = (const float*)(ws + 8 + LEV * KCODE);

    const int tid  = threadIdx.x;
    const int lane = tid & 63;
    const int wid  = tid >> 6;
    const int q    = lane >> 4;   // quad: owns dims st*32 + q*8 + j
    const int col  = lane & 15;   // B-operand col (code) in C layout
    const long tokbase = (long)blockIdx.x * 128 + wid * 32;

    // --- swizzled LDS offsets (bank-conflict-free staging) ---
    const int wc   = (((tid >> 2) & 3) << 6) | ((tid & 3) << 4) | (tid >> 4);
    const int woff = (wc ^ ((wc >> 4) & 7)) << 4;
    const int ro_e = (lane ^ (lane >> 4)) << 4;        // read offset, even ksteps (0,2)
    const int ro_o = (lane ^ 4 ^ (lane >> 4)) << 4;    // read offset, odd ksteps (1,3)

    float r[2][4][8];             // residual, fp32, reference-exact op chain
    f16x8 Ah[2][4], Al[2][4];     // A-frags: hi/lo fp16 split of (-2*residual)

    #pragma unroll
    for (int mt = 0; mt < 2; ++mt) {
        const float4* zp = (const float4*)(ze + (size_t)(tokbase + mt*16 + col) * DIMV);
        #pragma unroll
        for (int st = 0; st < 4; ++st) {
            float4 a = zp[st*8 + q*2], b = zp[st*8 + q*2 + 1];
            r[mt][st][0]=a.x; r[mt][st][1]=a.y; r[mt][st][2]=a.z; r[mt][st][3]=a.w;
            r[mt][st][4]=b.x; r[mt][st][5]=b.y; r[mt][st][6]=b.z; r[mt][st][7]=b.w;
        }
    }
    // A-frags scaled by -2 (exact power-of-2 scale), so MFMA accumulates eeq - 2*dot = d+8192
    #pragma unroll
    for (int mt = 0; mt < 2; ++mt)
        #pragma unroll
        for (int st = 0; st < 4; ++st) {
            f16x8 h, lo;
            #pragma unroll
            for (int j = 0; j < 8; ++j) {
                float y = -2.0f * r[mt][st][j];
                _Float16 hh = (_Float16)y;
                h[j] = hh;
                lo[j] = (_Float16)(y - (float)hh);
            }
            Ah[mt][st] = h; Al[mt][st] = lo;
        }

    double loss = 0.0;
    float* out_idx = out + (size_t)N_TOK * DIMV + 2;

    for (int l = 0; l < LEV; ++l) {
        __syncthreads();   // prior level's LDS users done
        ((float4*)eeS)[tid] = ((const float4*)(eebg + (size_t)l * KCODE))[tid];
        {   // prologue: stage tiles 0..3
            const float4* p = (const float4*)(cb + ((size_t)l*KCODE + (tid>>4)) * DIMV + (tid&15)*8);
            #pragma unroll
            for (int i = 0; i < 4; ++i) {
                stage_write(Bbuf[i], woff, p[0], p[1]);
                p += 512;   // 16 codes * 128 dims / 4
            }
        }
        __syncthreads();

        // running prefetch pointer: tile 4's chunk for this thread
        const float4* pp = (const float4*)(cb + ((size_t)l*KCODE + 64 + (tid>>4)) * DIMV + (tid&15)*8);

        unsigned m1[2][4], m2[2][4];
        #pragma unroll
        for (int mt = 0; mt < 2; ++mt)
            #pragma unroll
            for (int i = 0; i < 4; ++i) { m1[mt][i] = 0xFFFFFFFFu; m2[mt][i] = 0xFFFFFFFFu; }

        for (int tb = 0; tb < NTILES; tb += 4) {
            const int pre = (tb + 4 < NTILES);
            #pragma unroll
            for (int s = 0; s < 4; ++s) {
                const int t = tb + s;
                float4 g0, g1;
                if (pre) { g0 = pp[0]; g1 = pp[1]; pp += 512; }
                {
                    const unsigned char* bb = Bbuf[t & 7];
                    f16x8 B0 = *(const f16x8*)(bb + ro_e);
                    f16x8 B1 = *(const f16x8*)(bb + 1024 + ro_o);
                    f16x8 B2 = *(const f16x8*)(bb + 2048 + ro_e);
                    f16x8 B3 = *(const f16x8*)(bb + 3072 + ro_o);
                    float eeq = eeS[t*16 + col];
                    f32x4 c0  = {eeq, eeq, eeq, eeq};
                    f32x4 c1v = {eeq, eeq, eeq, eeq};
                    // k-major, alternating accumulators: dependency distance 2
                    c0  = __builtin_amdgcn_mfma_f32_16x16x32_f16(Ah[0][0], B0, c0, 0,0,0);
                    c1v = __builtin_amdgcn_mfma_f32_16x16x32_f16(Ah[1][0], B0, c1v, 0,0,0);
                    c0  = __builtin_amdgcn_mfma_f32_16x16x32_f16(Al[0][0], B0, c0, 0,0,0);
                    c1v = __builtin_amdgcn_mfma_f32_16x16x32_f16(Al[1][0], B0, c1v, 0,0,0);
                    c0  = __builtin_amdgcn_mfma_f32_16x16x32_f16(Ah[0][1], B1, c0, 0,0,0);
                    c1v = __builtin_amdgcn_mfma_f32_16x16x32_f16(Ah[1][1], B1, c1v, 0,0,0);
                    c0  = __builtin_amdgcn_mfma_f32_16x16x32_f16(Al[0][1], B1, c0, 0,0,0);
                    c1v = __builtin_amdgcn_mfma_f32_16x16x32_f16(Al[1][1], B1, c1v, 0,0,0);
                    c0  = __builtin_amdgcn_mfma_f32_16x16x32_f16(Ah[0][2], B2, c0, 0,0,0);
                    c1v = __builtin_amdgcn_mfma_f32_16x16x32_f16(Ah[1][2], B2, c1v, 0,0,0);
                    c0  = __builtin_amdgcn_mfma_f32_16x16x32_f16(Al[0][2], B2, c0, 0,0,0);
                    c1v = __builtin_amdgcn_mfma_f32_16x16x32_f16(Al[1][2], B2, c1v, 0,0,0);
                    c0  = __builtin_amdgcn_mfma_f32_16x16x32_f16(Ah[0][3], B3, c0, 0,0,0);
                    c1v = __builtin_amdgcn_mfma_f32_16x16x32_f16(Ah[1][3], B3, c1v, 0,0,0);
                    c0  = __builtin_amdgcn_mfma_f32_16x16x32_f16(Al[0][3], B3, c0, 0,0,0);
                    c1v = __builtin_amdgcn_mfma_f32_16x16x32_f16(Al[1][3], B3, c1v, 0,0,0);
                    #pragma unroll
                    for (int i = 0; i < 4; ++i) {
                        unsigned k0 = (__float_as_uint(c0[i]) << 6) | (unsigned)t;
                        m2[0][i] = min(m2[0][i], max(m1[0][i], k0));
                        m1[0][i] = min(m1[0][i], k0);
                        unsigned k1_ = (__float_as_uint(c1v[i]) << 6) | (unsigned)t;
                        m2[1][i] = min(m2[1][i], max(m1[1][i], k1_));
                        m1[1][i] = min(m1[1][i], k1_);
                    }
                }
                if (pre) stage_write(Bbuf[(t+4)&7], woff, g0, g1);
            }
            __syncthreads();
        }

        // ---- phase 2: cross-lane top-2 reduce (with lane-col meta), select, rescore, update ----
        unsigned k1[2][4], k2[2][4], q1[2][4], q2[2][4];
        #pragma unroll
        for (int mt = 0; mt < 2; ++mt)
            #pragma unroll
            for (int i = 0; i < 4; ++i) {
                k1[mt][i] = m1[mt][i]; k2[mt][i] = m2[mt][i];
                q1[mt][i] = (unsigned)col; q2[mt][i] = (unsigned)col;
            }
        #pragma unroll
        for (int d = 1; d <= 8; d <<= 1) {
            #pragma unroll
            for (int mt = 0; mt < 2; ++mt)
                #pragma unroll
                for (int i = 0; i < 4; ++i) {
                    unsigned ok1 = __shfl_xor(k1[mt][i], d), oq1 = __shfl_xor(q1[mt][i], d);
                    unsigned ok2 = __shfl_xor(k2[mt][i], d), oq2 = __shfl_xor(q2[mt][i], d);
                    bool sw = (ok1 < k1[mt][i]) || (ok1 == k1[mt][i] && oq1 < q1[mt][i]);
                    unsigned n1 = sw ? ok1 : k1[mt][i], nq1 = sw ? oq1 : q1[mt][i];
                    unsigned hk = sw ? k1[mt][i] : ok1, hq = sw ? q1[mt][i] : oq1;
                    bool s2 = (ok2 < k2[mt][i]) || (ok2 == k2[mt][i] && oq2 < q2[mt][i]);
                    unsigned p2 = s2 ? ok2 : k2[mt][i], pq = s2 ? oq2 : q2[mt][i];
                    bool s3 = (p2 < hk) || (p2 == hk && pq < hq);
                    k1[mt][i] = n1;              q1[mt][i] = nq1;
                    k2[mt][i] = s3 ? p2 : hk;    q2[mt][i] = s3 ? pq : hq;
                }
        }

        int jsel = (lane >> 2) & 3;
        int S = ((col >> 2) << 4) | ((col & 3) << 2);   // source lane holding token col's keys

        #pragma unroll
        for (int mt = 0; mt < 2; ++mt) {
            unsigned sk1 = sel4(k1[mt], jsel), sq1 = sel4(q1[mt], jsel);
            unsigned sk2 = sel4(k2[mt], jsel), sq2 = sel4(q2[mt], jsel);
            unsigned bk1 = (unsigned)__shfl((int)sk1, S);
            unsigned bq1 = (unsigned)__shfl((int)sq1, S);
            unsigned bk2 = (unsigned)__shfl((int)sk2, S);
            unsigned bq2 = (unsigned)__shfl((int)sq2, S);
            int c1c = (int)(((bk1 & 63u) << 4) | bq1);
            int c2c = (int)(((bk2 & 63u) << 4) | bq2);
            float d1 = __uint_as_float((bk1 >> 6) | 0x44000000u) - 8192.0f;
            float d2 = __uint_as_float((bk2 >> 6) | 0x44000000u) - 8192.0f;
            int bc = c1c;
            if (d2 - d1 < EPS) {   // ambiguous: exact fp64 rescore of both (uniform per token group)
                double s1 = 0.0, s2d = 0.0;
                const float4* e1 = (const float4*)(cb + ((size_t)l*KCODE + c1c)*DIMV);
                const float4* e2 = (const float4*)(cb + ((size_t)l*KCODE + c2c)*DIMV);
                #pragma unroll
                for (int st = 0; st < 4; ++st) {
                    float4 a = e1[st*8 + q*2], b = e1[st*8 + q*2 + 1];
                    s1 = fma((double)a.x,(double)r[mt][st][0],s1); s1 = fma((double)a.y,(double)r[mt][st][1],s1);
                    s1 = fma((double)a.z,(double)r[mt][st][2],s1); s1 = fma((double)a.w,(double)r[mt][st][3],s1);
                    s1 = fma((double)b.x,(double)r[mt][st][4],s1); s1 = fma((double)b.y,(double)r[mt][st][5],s1);
                    s1 = fma((double)b.z,(double)r[mt][st][6],s1); s1 = fma((double)b.w,(double)r[mt][st][7],s1);
                    float4 a2 = e2[st*8 + q*2], b2 = e2[st*8 + q*2 + 1];
                    s2d = fma((double)a2.x,(double)r[mt][st][0],s2d); s2d = fma((double)a2.y,(double)r[mt][st][1],s2d);
                    s2d = fma((double)a2.z,(double)r[mt][st][2],s2d); s2d = fma((double)a2.w,(double)r[mt][st][3],s2d);
                    s2d = fma((double)b2.x,(double)r[mt][st][4],s2d); s2d = fma((double)b2.y,(double)r[mt][st][5],s2d);
                    s2d = fma((double)b2.z,(double)r[mt][st][6],s2d); s2d = fma((double)b2.w,(double)r[mt][st][7],s2d);
                }
                s1  += __shfl_xor(s1, 16);  s1  += __shfl_xor(s1, 32);
                s2d += __shfl_xor(s2d, 16); s2d += __shfl_xor(s2d, 32);
                double dd1 = ee64g[l*KCODE + c1c] - 2.0*s1;
                double dd2 = ee64g[l*KCODE + c2c] - 2.0*s2d;
                if (dd2 < dd1 || (dd2 == dd1 && c2c < c1c)) bc = c2c;
            }
            // residual update: reference-exact fp32 op chain
            const float4* eb = (const float4*)(cb + ((size_t)l*KCODE + bc)*DIMV);
            #pragma unroll
            for (int st = 0; st < 4; ++st) {
                float4 a = eb[st*8 + q*2], b = eb[st*8 + q*2 + 1];
                float qv[8] = {a.x,a.y,a.z,a.w,b.x,b.y,b.z,b.w};
                #pragma unroll
                for (int j = 0; j < 8; ++j) {
                    float rv = r[mt][st][j];
                    float t1 = qv[j] - rv;              // z_q - residual
                    loss += (double)t1 * (double)t1;
                    float zqst = rv + t1;               // straight-through
                    r[mt][st][j] = rv - zqst;
                }
            }
            if (l < LEV - 1) {   // rebuild A-frags (scaled by -2) for next level
                #pragma unroll
                for (int st = 0; st < 4; ++st) {
                    f16x8 h, lo;
                    #pragma unroll
                    for (int j = 0; j < 8; ++j) {
                        float y = -2.0f * r[mt][st][j];
                        _Float16 hh = (_Float16)y;
                        h[j] = hh;
                        lo[j] = (_Float16)(y - (float)hh);
                    }
                    Ah[mt][st] = h; Al[mt][st] = lo;
                }
            } else {             // final output: z_q_total = z_e - residual_final
                const float4* zp = (const float4*)(ze + (size_t)(tokbase + mt*16 + col)*DIMV);
                float4* op = (float4*)(out + (size_t)(tokbase + mt*16 + col)*DIMV);
                #pragma unroll
                for (int st = 0; st < 4; ++st) {
                    float4 za = zp[st*8 + q*2], zb = zp[st*8 + q*2 + 1];
                    float4 oa, ob;
                    oa.x = za.x - r[mt][st][0]; oa.y = za.y - r[mt][st][1];
                    oa.z = za.z - r[mt][st][2]; oa.w = za.w - r[mt][st][3];
                    ob.x = zb.x - r[mt][st][4]; ob.y = zb.y - r[mt][st][5];
                    ob.z = zb.z - r[mt][st][6]; ob.w = zb.w - r[mt][st][7];
                    op[st*8 + q*2] = oa; op[st*8 + q*2 + 1] = ob;
                }
            }
            if (q == 0) out_idx[(size_t)(tokbase + mt*16 + col)*3 + l] = (float)bc;
        }
    }

    #pragma unroll
    for (int d = 1; d <= 32; d <<= 1) loss += __shfl_xor(loss, d);
    if ((tid & 63) == 0) ssum[wid] = loss;
    __syncthreads();
    if (tid == 0) atomicAdd(ws, ssum[0] + ssum[1] + ssum[2] + ssum[3]);
}

__global__ void rvq_fin(const double* __restrict__ ws, float* __restrict__ out) {
    double vq = ws[0] / ((double)N_TOK * (double)DIMV * (double)LEV);
    out[(size_t)N_TOK * DIMV + 0] = (float)vq;
    out[(size_t)N_TOK * DIMV + 1] = (float)(0.25 * vq);
}

extern "C" void kernel_launch(void* const* d_in, const int* in_sizes, int n_in,
                              void* d_out, int out_size, void* d_ws, size_t ws_size,
                              hipStream_t stream) {
    const float* ze = (const float*)d_in[0];
    const float* cb = (const float*)d_in[1];
    float* out = (float*)d_out;
    double* ws = (double*)d_ws;

    rvq_prep<<<(LEV * KCODE + 255) / 256, 256, 0, stream>>>(cb, ws);
    rvq_main<<<N_TOK / 128, BLOCK, 0, stream>>>(ze, cb, out, ws);
    rvq_fin<<<1, 1, 0, stream>>>(ws, out);
}